// Round 13
// baseline (211.464 us; speedup 1.0000x reference)
//
#include <hip/hip_runtime.h>
#include <hip/hip_cooperative_groups.h>

namespace cg = cooperative_groups;

#define BATCH 8
#define NBOX 2000
#define NCLS 81
#define NPAD 2048
#define MAX_OUT 300
#define SCORE_T 0.05f
#define IOU_T 0.5f
#define MASK_WORDS 64   /* 2048 cols / 32 bits */
#define WDEPTH 64       /* candidates per walk iteration */
#define NBLK 256
#define NTHR 512

// ---- ws byte offsets ----
#define WS_BOXES   0          // float4[16000]           256000
#define WS_SCORES  256000     // float [16000]            64000
#define WS_SKEY    320000     // u64   [8*2048]          131072
#define WS_SBOX    451072     // float4[8*2048]          262144
#define WS_LARR    713216     // int[8]                      32
#define WS_KLIST   713248     // int[8*300]                9600
#define WS_KCOUNT  722848     // int[8]                      32
#define WS_MASK    786432     // uint[8*2048*64]        4194304  (end ~4.98 MB)

__global__ __launch_bounds__(NTHR) void mega_kernel(
        const float* __restrict__ deltas,
        const float* __restrict__ logits,
        const float* __restrict__ proposals,
        float4* __restrict__ boxes,
        float* __restrict__ scores,
        unsigned long long* __restrict__ skey,
        float4* __restrict__ sbox,
        int* __restrict__ Larr,
        int* __restrict__ klist,
        int* __restrict__ kcount,
        unsigned int* __restrict__ mask,
        float* __restrict__ out) {
    cg::grid_group grid = cg::this_grid();
    int bid = blockIdx.x;
    int t = threadIdx.x;
    int gtid = bid * NTHR + t;

    __shared__ __align__(16) char smem[(NPAD + 16) * 16];   // 33 KB union

    // ================= phase P: prep (8 lanes per box) =================
    {
        if (gtid < BATCH) Larr[gtid] = 0;
        int g = gtid >> 3;
        int j = t & 7;
        if (g < BATCH * NBOX) {
            const float* l = logits + (long)g * NCLS;
            float M = -3.0e38f;
            float bl = -3.0e38f; int bc = 0;
            for (int c = j; c < NCLS; c += 8) {
                float v = l[c];
                M = fmaxf(M, v);
                if (c >= 1 && v > bl) { bl = v; bc = c; }
            }
            #pragma unroll
            for (int off = 1; off < 8; off <<= 1)
                M = fmaxf(M, __shfl_xor(M, off));
            float S = 0.f;
            for (int c = j; c < NCLS; c += 8) S += expf(l[c] - M);
            #pragma unroll
            for (int off = 1; off < 8; off <<= 1) S += __shfl_xor(S, off);
            #pragma unroll
            for (int off = 1; off < 8; off <<= 1) {
                float ov = __shfl_xor(bl, off);
                int   oi = __shfl_xor(bc, off);
                if (ov > bl || (ov == bl && oi < bc)) { bl = ov; bc = oi; }
            }
            if (j == 0) {
                float score = expf(bl - M) / S;
                const float* p = proposals + (long)g * 5;
                float y1 = p[0], x1 = p[1], y2 = p[2], x2 = p[3];
                float h = y2 - y1, w = x2 - x1;
                float cy = (y2 + y1) * 0.5f, cx = (x2 + x1) * 0.5f;
                const float* dd = deltas + ((long)g * NCLS + bc) * 4;
                float d0 = dd[0] * 0.1f, d1 = dd[1] * 0.1f;
                float d2 = dd[2] * 0.2f, d3 = dd[3] * 0.2f;
                cy = cy + d0 * h;
                cx = cx + d1 * w;
                h = h * expf(d2);
                w = w * expf(d3);
                boxes[g] = make_float4(cy - h * 0.5f, cx - w * 0.5f,
                                       cy + h * 0.5f, cx + w * 0.5f);
                scores[g] = score;
            }
        }
    }
    grid.sync();

    // ================= phase R: rank (stable descending sort) =================
    {
        unsigned long long* s_key = (unsigned long long*)smem;
        int (*s_part)[8] = (int(*)[8])(void*)(smem + (NPAD + 16) * 8);
        int b = bid & 7, rb = bid >> 3;

        for (int c = t; c < NPAD; c += NTHR) {
            unsigned int bits = 0u;
            if (c < NBOX) bits = __float_as_uint(scores[b * NBOX + c]);
            s_key[c + (c >> 7)] =
                ((unsigned long long)bits << 32) |
                (unsigned long long)(0xFFFFFFFFu - (unsigned)c);
        }
        __syncthreads();

        int own = rb * 64 + (t >> 3);
        int seg = t & 7;
        unsigned long long mykey = s_key[own + (own >> 7)];
        int cnt = 0;
        int cbase = seg * 256;
        #pragma unroll 4
        for (int jj = 0; jj < 256; ++jj) {
            int c = cbase + jj;
            cnt += (s_key[c + (c >> 7)] > mykey) ? 1 : 0;
        }
        s_part[t >> 3][seg] = cnt;
        __syncthreads();

        if (t < 64) {
            int own2 = rb * 64 + t;
            unsigned long long key = s_key[own2 + (own2 >> 7)];
            int rank = s_part[t][0] + s_part[t][1] + s_part[t][2] + s_part[t][3]
                     + s_part[t][4] + s_part[t][5] + s_part[t][6] + s_part[t][7];
            skey[b * NPAD + rank] = key;
            unsigned int orig = 0xFFFFFFFFu - (unsigned int)key;
            float4 bx = make_float4(0.f, 0.f, 0.f, 0.f);
            if (orig < NBOX) bx = boxes[b * NBOX + orig];
            sbox[b * NPAD + rank] = bx;
            float sc = __uint_as_float((unsigned int)(key >> 32));
            if (sc > SCORE_T) atomicMax(&Larr[b], rank + 1);
        }
    }
    grid.sync();

    // ================= phase M: mask (upper-tri x alive-prefix) =================
    {
        int b = bid & 7, rb = bid >> 3;
        int L = Larr[b];
        if (rb * 64 < L) {                 // block-uniform: barriers legal inside
            float4* s_bx = (float4*)smem;
            for (int c = t; c < NPAD; c += NTHR)
                s_bx[c + (c >> 7)] = sbox[b * NPAD + c];
            __syncthreads();

            int r   = rb * 64 + (t & 63);
            int seg = t >> 6;
            float4 rbx = s_bx[r + (r >> 7)];
            float rar = (rbx.z - rbx.x) * (rbx.w - rbx.y);
            unsigned int* outp = mask + (((size_t)(b * NPAD + r)) << 6);

            for (int w = 0; w < 8; ++w) {
                int wi = (seg << 3) + w;
                unsigned int bits = 0u;
                int colbase = wi << 5;
                if (colbase + 31 > r && colbase < L) {
                    #pragma unroll 8
                    for (int c2 = 0; c2 < 32; ++c2) {
                        int col = colbase + c2;
                        float4 ob = s_bx[col + (col >> 7)];
                        float oa = (ob.z - ob.x) * (ob.w - ob.y);
                        float yy1 = fmaxf(rbx.x, ob.x), xx1 = fmaxf(rbx.y, ob.y);
                        float yy2 = fminf(rbx.z, ob.z), xx2 = fminf(rbx.w, ob.w);
                        float inter = fmaxf(yy2 - yy1, 0.f) * fmaxf(xx2 - xx1, 0.f);
                        float iou = inter / (rar + oa - inter + 1e-8f);
                        bits |= (iou > IOU_T) ? (1u << c2) : 0u;
                    }
                }
                outp[wi] = bits;
            }
        }
    }
    grid.sync();

    // ================= phase W: walk (blocks 0-7, wave 0, barrier-free) =========
    if (bid < BATCH && t < 64) {
        int b = bid;
        int lane = t;
        int* s_cand = (int*)smem;

        int L = Larr[b];
        int nset = L - (lane << 5);
        nset = nset < 0 ? 0 : (nset > 32 ? 32 : nset);
        unsigned int alive = (nset >= 32) ? 0xFFFFFFFFu
                            : ((nset <= 0) ? 0u : ((1u << nset) - 1u));

        const unsigned int* M = mask + ((size_t)b * NPAD) * MASK_WORDS;
        int kept = 0;

        while (kept < MAX_OUT) {
            unsigned long long ne = __ballot(alive != 0u);
            if (!ne) break;

            // parallel extraction of first up-to-64 alive (ascending rank)
            int mypc = __builtin_popcount(alive);
            int incl = mypc;
            #pragma unroll
            for (int off = 1; off < 64; off <<= 1) {
                int n = __shfl_up(incl, off);
                if (lane >= off) incl += n;
            }
            int excl = incl - mypc;
            int total = __builtin_amdgcn_readlane(incl, 63);
            int ncand = total < WDEPTH ? total : WDEPTH;

            {   // each lane peels its own word into s_cand (intra-wave LDS)
                unsigned int aw = alive;
                int pos = excl;
                while (aw && pos < WDEPTH) {
                    int bit = (int)__builtin_ctz(aw);
                    aw &= aw - 1u;
                    s_cand[pos] = (lane << 5) + bit;
                    pos++;
                }
            }
            asm volatile("s_waitcnt lgkmcnt(0)" ::: "memory");  // wave-internal order

            int candv = s_cand[lane < ncand ? lane : 0];

            int cdsc[WDEPTH];
            #pragma unroll
            for (int d = 0; d < WDEPTH; ++d)
                cdsc[d] = __builtin_amdgcn_readlane(candv, d);

            // rowA[d]: word `lane` of row cand_d (alive update)
            unsigned int rowA[WDEPTH];
            #pragma unroll
            for (int d = 0; d < WDEPTH; ++d)
                rowA[d] = M[((size_t)cdsc[d] << 6) + lane];

            // colw[e]: word of row cand_e containing MY candidate's bit
            int myw = candv >> 5;
            int sh = candv & 31;
            unsigned int colw[WDEPTH];
            #pragma unroll
            for (int e = 0; e < WDEPTH; ++e)
                colw[e] = M[((size_t)cdsc[e] << 6) + myw];

            // transpose -> scalar masks sub[e] (bit d = e suppresses d)
            unsigned long long sub[WDEPTH];
            #pragma unroll
            for (int e = 0; e < WDEPTH; ++e)
                sub[e] = __ballot(((colw[e] >> sh) & 1u) != 0u);

            // scalar greedy resolve (exact order + MAX_OUT truncation)
            unsigned long long live =
                (ncand >= 64) ? ~0ull : ((1ull << ncand) - 1ull);
            unsigned long long committed = 0ull;
            int kept_base = kept;
            #pragma unroll
            for (int e = 0; e < WDEPTH; ++e) {
                if (kept < MAX_OUT && ((live >> e) & 1ull)) {
                    committed |= 1ull << e;
                    kept++;
                    live &= ~sub[e];
                }
            }

            // alive update: committed rows clear their suppressees
            unsigned int acc = 0u;
            #pragma unroll
            for (int d = 0; d < WDEPTH; ++d) {
                unsigned int m = 0u - (unsigned int)((committed >> d) & 1ull);
                acc |= rowA[d] & m;
            }
            alive &= ~acc;

            // clear committed candidates' own bits (uniform scalar guards)
            #pragma unroll
            for (int d = 0; d < WDEPTH; ++d) {
                if ((committed >> d) & 1ull) {
                    if (lane == (cdsc[d] >> 5))
                        alive &= ~(1u << (cdsc[d] & 31));
                }
            }

            // record kept ids directly to global (rank via popcount)
            if (lane < ncand && ((committed >> lane) & 1ull)) {
                int pos = kept_base +
                    (int)__builtin_popcountll(committed & ((1ull << lane) - 1ull));
                klist[b * MAX_OUT + pos] = candv;
            }
        }
        if (lane == 0) kcount[b] = kept;
    }
    grid.sync();

    // ================= phase O: outputs (grid-stride, zero-fill) =================
    {
        const int NB = BATCH * MAX_OUT * 5;
        const int NS = BATCH * MAX_OUT * 2;
        const int NL = BATCH * MAX_OUT * NCLS;
        const int TOT = NB + NS + NL;
        for (int idx = gtid; idx < TOT; idx += NBLK * NTHR) {
            float v = 0.f;
            if (idx < NB) {
                int b = idx / (MAX_OUT * 5);
                int rem = idx - b * (MAX_OUT * 5);
                int k = rem / 5, c = rem - 5 * k;
                if (k < kcount[b]) {
                    if (c == 4) v = 1.f;
                    else {
                        float4 bx = sbox[b * NPAD + klist[b * MAX_OUT + k]];
                        v = (c == 0) ? bx.x : (c == 1) ? bx.y
                          : (c == 2) ? bx.z : bx.w;
                    }
                }
            } else if (idx < NB + NS) {
                int jj = idx - NB;
                int b = jj / (MAX_OUT * 2);
                int rem = jj - b * (MAX_OUT * 2);
                int k = rem >> 1, c = rem & 1;
                if (k < kcount[b]) {
                    if (c) v = 1.f;
                    else v = __uint_as_float((unsigned int)
                             (skey[b * NPAD + klist[b * MAX_OUT + k]] >> 32));
                }
            } else {
                int jj = idx - NB - NS;
                int b = jj / (MAX_OUT * NCLS);
                int rem = jj - b * (MAX_OUT * NCLS);
                int k = rem / NCLS, c = rem - NCLS * k;
                if (k < kcount[b]) {
                    unsigned long long key = skey[b * NPAD + klist[b * MAX_OUT + k]];
                    unsigned int orig = 0xFFFFFFFFu - (unsigned int)key;
                    v = logits[((long)b * NBOX + orig) * NCLS + c];
                }
            }
            out[idx] = v;
        }
    }
}

extern "C" void kernel_launch(void* const* d_in, const int* in_sizes, int n_in,
                              void* d_out, int out_size, void* d_ws, size_t ws_size,
                              hipStream_t stream) {
    const float* deltas    = (const float*)d_in[0];
    const float* logits    = (const float*)d_in[1];
    const float* proposals = (const float*)d_in[2];
    float* out = (float*)d_out;

    char* ws = (char*)d_ws;
    float4* ws_boxes  = (float4*)(ws + WS_BOXES);
    float*  ws_scores = (float*)(ws + WS_SCORES);
    unsigned long long* ws_skey = (unsigned long long*)(ws + WS_SKEY);
    float4* ws_sbox   = (float4*)(ws + WS_SBOX);
    int*    ws_Larr   = (int*)(ws + WS_LARR);
    int*    ws_klist  = (int*)(ws + WS_KLIST);
    int*    ws_kcount = (int*)(ws + WS_KCOUNT);
    unsigned int* ws_mask = (unsigned int*)(ws + WS_MASK);

    void* args[] = {
        (void*)&deltas, (void*)&logits, (void*)&proposals,
        (void*)&ws_boxes, (void*)&ws_scores, (void*)&ws_skey,
        (void*)&ws_sbox, (void*)&ws_Larr, (void*)&ws_klist,
        (void*)&ws_kcount, (void*)&ws_mask, (void*)&out
    };
    hipLaunchCooperativeKernel((void*)mega_kernel, dim3(NBLK), dim3(NTHR),
                               args, 0, stream);
}

// Round 14
// 125.643 us; speedup vs baseline: 1.6831x; 1.6831x over previous
//
#include <hip/hip_runtime.h>

#define BATCH 8
#define NBOX 2000
#define NCLS 81
#define NPAD 2048
#define MAX_OUT 300
#define SCORE_T 0.05f
#define IOU_T 0.5f
#define MASK_WORDS 64   /* 2048 cols / 32 bits */
#define WDEPTH 64       /* candidates per walk iteration */

// ---- ws byte offsets ----
#define WS_BOXES   0          // float4[16000]           256000
#define WS_SCORES  256000     // float [16000]            64000
#define WS_SKEY    320000     // u64   [8*2048]          131072
#define WS_SBOX    451072     // float4[8*2048]          262144
#define WS_LARR    713216     // int[8]                      32
#define WS_KLIST   713248     // int[8*300]                9600
#define WS_KCOUNT  722848     // int[8]                      32
#define WS_MASK    786432     // uint[8*2048*64]        4194304  (end ~4.98 MB)

// ------- prep: 8 lanes per box, coalesced logits + shuffle-tree reduce -------
__global__ __launch_bounds__(256) void prep_kernel(
        const float* __restrict__ deltas,
        const float* __restrict__ logits,
        const float* __restrict__ proposals,
        float4* __restrict__ boxes_out,
        float* __restrict__ scores_out,
        int* __restrict__ Larr) {
    int gtid = blockIdx.x * 256 + threadIdx.x;
    if (gtid < BATCH) Larr[gtid] = 0;        // zero before rank's atomicMax
    int g = gtid >> 3;                       // box id
    int j = threadIdx.x & 7;                 // sub-lane 0..7
    if (g >= BATCH * NBOX) return;

    const float* l = logits + (long)g * NCLS;
    float M = -3.0e38f;
    float bl = -3.0e38f; int bc = 0;
    for (int c = j; c < NCLS; c += 8) {
        float v = l[c];
        M = fmaxf(M, v);
        if (c >= 1 && v > bl) { bl = v; bc = c; }
    }
    #pragma unroll
    for (int off = 1; off < 8; off <<= 1)
        M = fmaxf(M, __shfl_xor(M, off));
    float S = 0.f;
    for (int c = j; c < NCLS; c += 8) S += expf(l[c] - M);
    #pragma unroll
    for (int off = 1; off < 8; off <<= 1) S += __shfl_xor(S, off);
    #pragma unroll
    for (int off = 1; off < 8; off <<= 1) {
        float ov = __shfl_xor(bl, off);
        int   oi = __shfl_xor(bc, off);
        if (ov > bl || (ov == bl && oi < bc)) { bl = ov; bc = oi; }
    }
    if (j == 0) {
        float score = expf(bl - M) / S;
        const float* p = proposals + (long)g * 5;
        float y1 = p[0], x1 = p[1], y2 = p[2], x2 = p[3];
        float h = y2 - y1, w = x2 - x1;
        float cy = (y2 + y1) * 0.5f, cx = (x2 + x1) * 0.5f;
        const float* dd = deltas + ((long)g * NCLS + bc) * 4;
        float d0 = dd[0] * 0.1f, d1 = dd[1] * 0.1f;
        float d2 = dd[2] * 0.2f, d3 = dd[3] * 0.2f;
        cy = cy + d0 * h;
        cx = cx + d1 * w;
        h = h * expf(d2);
        w = w * expf(d3);
        boxes_out[g] = make_float4(cy - h * 0.5f, cx - w * 0.5f,
                                   cy + h * 0.5f, cx + w * 0.5f);
        scores_out[g] = score;
    }
}

// ---- rank: stable descending sort via direct rank, 512 thr (2 waves/SIMD) ----
__global__ __launch_bounds__(512) void rank_kernel(
        const float* __restrict__ scores,
        const float4* __restrict__ boxes,
        unsigned long long* __restrict__ skey,
        float4* __restrict__ sbox,
        int* __restrict__ Larr) {
    int bid = blockIdx.x;
    int b = bid & 7, rb = bid >> 3;      // batch = bid%8 -> XCD locality
    int t = threadIdx.x;

    __shared__ unsigned long long s_key[NPAD + 16];
    __shared__ int s_part[64][8];

    for (int c = t; c < NPAD; c += 512) {
        unsigned int bits = 0u;
        if (c < NBOX) bits = __float_as_uint(scores[b * NBOX + c]);
        s_key[c + (c >> 7)] =
            ((unsigned long long)bits << 32) |
            (unsigned long long)(0xFFFFFFFFu - (unsigned)c);
    }
    __syncthreads();

    int own = rb * 64 + (t >> 3);
    int seg = t & 7;
    unsigned long long mykey = s_key[own + (own >> 7)];
    int cnt = 0;
    int cbase = seg * 256;
    #pragma unroll 4
    for (int jj = 0; jj < 256; ++jj) {
        int c = cbase + jj;
        cnt += (s_key[c + (c >> 7)] > mykey) ? 1 : 0;
    }
    s_part[t >> 3][seg] = cnt;
    __syncthreads();

    if (t < 64) {
        int own2 = rb * 64 + t;
        unsigned long long key = s_key[own2 + (own2 >> 7)];
        int rank = s_part[t][0] + s_part[t][1] + s_part[t][2] + s_part[t][3]
                 + s_part[t][4] + s_part[t][5] + s_part[t][6] + s_part[t][7];
        skey[b * NPAD + rank] = key;
        unsigned int orig = 0xFFFFFFFFu - (unsigned int)key;
        float4 bx = make_float4(0.f, 0.f, 0.f, 0.f);
        if (orig < NBOX) bx = boxes[b * NBOX + orig];
        sbox[b * NPAD + rank] = bx;
        float sc = __uint_as_float((unsigned int)(key >> 32));
        if (sc > SCORE_T) atomicMax(&Larr[b], rank + 1);
    }
}

// ---- mask: upper-triangle x alive-prefix compute, full-row stores, 512 thr ----
__global__ __launch_bounds__(512) void mask_kernel(
        const float4* __restrict__ sbox,
        const int* __restrict__ Larr,
        unsigned int* __restrict__ mask) {
    int bid = blockIdx.x;
    int b = bid & 7, rb = bid >> 3;      // batch = bid%8 -> same XCD as walk block b
    int L = Larr[b];
    if (rb * 64 >= L) return;            // uniform: no row of this block is ever read
    int t = threadIdx.x;

    __shared__ float4 s_bx[NPAD + 16];

    for (int c = t; c < NPAD; c += 512)
        s_bx[c + (c >> 7)] = sbox[b * NPAD + c];
    __syncthreads();

    int r   = rb * 64 + (t & 63);        // lanes of a wave = 64 consecutive rows
    int seg = t >> 6;                    // word segment 0..7 (8 words each)
    float4 rbx = s_bx[r + (r >> 7)];
    float rar = (rbx.z - rbx.x) * (rbx.w - rbx.y);
    unsigned int* outp = mask + (((size_t)(b * NPAD + r)) << 6);

    for (int w = 0; w < 8; ++w) {
        int wi = (seg << 3) + w;
        unsigned int bits = 0u;
        int colbase = wi << 5;
        if (colbase + 31 > r && colbase < L) {
            #pragma unroll 8
            for (int c2 = 0; c2 < 32; ++c2) {
                int col = colbase + c2;
                float4 ob = s_bx[col + (col >> 7)];
                float oa = (ob.z - ob.x) * (ob.w - ob.y);
                float yy1 = fmaxf(rbx.x, ob.x), xx1 = fmaxf(rbx.y, ob.y);
                float yy2 = fminf(rbx.z, ob.z), xx2 = fminf(rbx.w, ob.w);
                float inter = fmaxf(yy2 - yy1, 0.f) * fmaxf(xx2 - xx1, 0.f);
                float iou = inter / (rar + oa - inter + 1e-8f);  // IEEE fdiv: exact vs ref
                bits |= (iou > IOU_T) ? (1u << c2) : 0u;
            }
        }
        outp[wi] = bits;
    }
}

// ---- walk: 64-candidate batches, parallel extraction + ballot-transpose
//      resolve; colw via shuffle from rowA (halves loads); 1 wave, no barriers ----
__global__ __launch_bounds__(64) void walk_kernel(
        const int* __restrict__ Larr,
        const unsigned int* __restrict__ mask,
        int* __restrict__ klist,
        int* __restrict__ kcount) {
    int b = blockIdx.x;
    int lane = threadIdx.x;

    __shared__ int s_cand[WDEPTH];

    int L = Larr[b];
    int nset = L - (lane << 5);
    nset = nset < 0 ? 0 : (nset > 32 ? 32 : nset);
    unsigned int alive = (nset >= 32) ? 0xFFFFFFFFu
                        : ((nset <= 0) ? 0u : ((1u << nset) - 1u));

    const unsigned int* M = mask + ((size_t)b * NPAD) * MASK_WORDS;
    int kept = 0;

    while (kept < MAX_OUT) {
        unsigned long long ne = __ballot(alive != 0u);
        if (!ne) break;

        // parallel extraction of first up-to-64 alive (ascending rank)
        int mypc = __builtin_popcount(alive);
        int incl = mypc;
        #pragma unroll
        for (int off = 1; off < 64; off <<= 1) {
            int n = __shfl_up(incl, off);
            if (lane >= off) incl += n;
        }
        int excl = incl - mypc;
        int total = __builtin_amdgcn_readlane(incl, 63);
        int ncand = total < WDEPTH ? total : WDEPTH;

        {   // each lane peels its own word into s_cand (wave-internal LDS)
            unsigned int aw = alive;
            int pos = excl;
            while (aw && pos < WDEPTH) {
                int bit = (int)__builtin_ctz(aw);
                aw &= aw - 1u;
                s_cand[pos] = (lane << 5) + bit;
                pos++;
            }
        }
        asm volatile("s_waitcnt lgkmcnt(0)" ::: "memory");  // 1 wave: order LDS w->r

        int candv = s_cand[lane < ncand ? lane : 0];

        int cdsc[WDEPTH];
        #pragma unroll
        for (int d = 0; d < WDEPTH; ++d)
            cdsc[d] = __builtin_amdgcn_readlane(candv, d);

        // rowA[d]: word `lane` of row cand_d (only memory loads this iter)
        unsigned int rowA[WDEPTH];
        #pragma unroll
        for (int d = 0; d < WDEPTH; ++d)
            rowA[d] = M[((size_t)cdsc[d] << 6) + lane];

        // colw[e] = M[cand_e][myw] = rowA[e] at lane myw -> shuffle, no loads
        int myw = candv >> 5;
        int sh = candv & 31;

        // transpose -> scalar masks sub[e] (bit d = e suppresses d)
        unsigned long long sub[WDEPTH];
        #pragma unroll
        for (int e = 0; e < WDEPTH; ++e) {
            unsigned int cw = (unsigned int)__shfl((int)rowA[e], myw);
            sub[e] = __ballot(((cw >> sh) & 1u) != 0u);
        }

        // scalar greedy resolve (exact order + MAX_OUT truncation)
        unsigned long long live =
            (ncand >= 64) ? ~0ull : ((1ull << ncand) - 1ull);
        unsigned long long committed = 0ull;
        int kept_base = kept;
        #pragma unroll
        for (int e = 0; e < WDEPTH; ++e) {
            if (kept < MAX_OUT && ((live >> e) & 1ull)) {
                committed |= 1ull << e;
                kept++;
                live &= ~sub[e];
            }
        }

        // alive update: committed rows clear their suppressees (branchless)
        unsigned int acc = 0u;
        #pragma unroll
        for (int d = 0; d < WDEPTH; ++d) {
            unsigned int m = 0u - (unsigned int)((committed >> d) & 1ull);
            acc |= rowA[d] & m;
        }
        alive &= ~acc;

        // clear committed candidates' own bits (uniform scalar guards)
        #pragma unroll
        for (int d = 0; d < WDEPTH; ++d) {
            if ((committed >> d) & 1ull) {
                if (lane == (cdsc[d] >> 5))
                    alive &= ~(1u << (cdsc[d] & 31));
            }
        }

        // record kept ids directly to global (rank via popcount)
        if (lane < ncand && ((committed >> lane) & 1ull)) {
            int pos = kept_base +
                (int)__builtin_popcountll(committed & ((1ull << lane) - 1ull));
            klist[b * MAX_OUT + pos] = candv;
        }
    }
    if (lane == 0) kcount[b] = kept;
}

// ---------------- outputs: parallel gather + zero-fill ----------------
__global__ void out_kernel(const unsigned long long* __restrict__ skey,
                           const float4* __restrict__ sbox,
                           const int* __restrict__ klist,
                           const int* __restrict__ kcount,
                           const float* __restrict__ logits,
                           float* __restrict__ out) {
    int idx = blockIdx.x * blockDim.x + threadIdx.x;
    const int NB = BATCH * MAX_OUT * 5;        // 12000
    const int NS = BATCH * MAX_OUT * 2;        // 4800
    const int NL = BATCH * MAX_OUT * NCLS;     // 194400
    if (idx >= NB + NS + NL) return;

    if (idx < NB) {
        int b = idx / (MAX_OUT * 5);
        int rem = idx - b * (MAX_OUT * 5);
        int k = rem / 5, c = rem - 5 * k;
        float v = 0.f;
        if (k < kcount[b]) {
            if (c == 4) v = 1.f;
            else {
                float4 bx = sbox[b * NPAD + klist[b * MAX_OUT + k]];
                v = (c == 0) ? bx.x : (c == 1) ? bx.y : (c == 2) ? bx.z : bx.w;
            }
        }
        out[idx] = v;
    } else if (idx < NB + NS) {
        int j = idx - NB;
        int b = j / (MAX_OUT * 2);
        int rem = j - b * (MAX_OUT * 2);
        int k = rem >> 1, c = rem & 1;
        float v = 0.f;
        if (k < kcount[b]) {
            if (c) v = 1.f;
            else {
                unsigned long long key = skey[b * NPAD + klist[b * MAX_OUT + k]];
                v = __uint_as_float((unsigned int)(key >> 32));
            }
        }
        out[idx] = v;
    } else {
        int j = idx - NB - NS;
        int b = j / (MAX_OUT * NCLS);
        int rem = j - b * (MAX_OUT * NCLS);
        int k = rem / NCLS, c = rem - NCLS * k;
        float v = 0.f;
        if (k < kcount[b]) {
            unsigned long long key = skey[b * NPAD + klist[b * MAX_OUT + k]];
            unsigned int orig = 0xFFFFFFFFu - (unsigned int)key;
            v = logits[((long)b * NBOX + orig) * NCLS + c];
        }
        out[idx] = v;
    }
}

extern "C" void kernel_launch(void* const* d_in, const int* in_sizes, int n_in,
                              void* d_out, int out_size, void* d_ws, size_t ws_size,
                              hipStream_t stream) {
    const float* deltas    = (const float*)d_in[0];
    const float* logits    = (const float*)d_in[1];
    const float* proposals = (const float*)d_in[2];
    float* out = (float*)d_out;

    char* ws = (char*)d_ws;
    float4* ws_boxes  = (float4*)(ws + WS_BOXES);
    float*  ws_scores = (float*)(ws + WS_SCORES);
    unsigned long long* ws_skey = (unsigned long long*)(ws + WS_SKEY);
    float4* ws_sbox   = (float4*)(ws + WS_SBOX);
    int*    ws_Larr   = (int*)(ws + WS_LARR);
    int*    ws_klist  = (int*)(ws + WS_KLIST);
    int*    ws_kcount = (int*)(ws + WS_KCOUNT);
    unsigned int* ws_mask = (unsigned int*)(ws + WS_MASK);

    prep_kernel<<<(BATCH * NBOX * 8 + 255) / 256, 256, 0, stream>>>(
        deltas, logits, proposals, ws_boxes, ws_scores, ws_Larr);
    rank_kernel<<<BATCH * (NPAD / 64), 512, 0, stream>>>(
        ws_scores, ws_boxes, ws_skey, ws_sbox, ws_Larr);
    mask_kernel<<<BATCH * (NPAD / 64), 512, 0, stream>>>(
        ws_sbox, ws_Larr, ws_mask);
    walk_kernel<<<BATCH, 64, 0, stream>>>(
        ws_Larr, ws_mask, ws_klist, ws_kcount);
    int total_out = BATCH * MAX_OUT * (5 + 2 + NCLS);
    out_kernel<<<(total_out + 255) / 256, 256, 0, stream>>>(
        ws_skey, ws_sbox, ws_klist, ws_kcount, logits, out);
}

// Round 16
// 97.997 us; speedup vs baseline: 2.1579x; 1.2821x over previous
//
#include <hip/hip_runtime.h>

#define BATCH 8
#define NBOX 2000
#define NCLS 81
#define NPAD 2048
#define MAX_OUT 300
#define SCORE_T 0.05f
#define IOU_T 0.5f
#define MASK_WORDS 64   /* 2048 cols / 32 bits */
#define WDEPTH 64       /* candidates per walk iteration */

// ---- ws byte offsets ----
#define WS_BOXES   0          // float4[16000]           256000
#define WS_SCORES  256000     // float [16000]            64000
#define WS_SKEY    320000     // u64   [8*2048]          131072
#define WS_SBOX    451072     // float4[8*2048]          262144
#define WS_LARR    713216     // int[8]                      32
#define WS_KLIST   713248     // int[8*300]                9600
#define WS_KCOUNT  722848     // int[8]                      32
#define WS_MASK    786432     // uint[8*2048*64]        4194304  (end ~4.98 MB)

// ------- prep: 8 lanes per box, coalesced logits + shuffle-tree reduce -------
__global__ __launch_bounds__(256) void prep_kernel(
        const float* __restrict__ deltas,
        const float* __restrict__ logits,
        const float* __restrict__ proposals,
        float4* __restrict__ boxes_out,
        float* __restrict__ scores_out,
        int* __restrict__ Larr) {
    int gtid = blockIdx.x * 256 + threadIdx.x;
    if (gtid < BATCH) Larr[gtid] = 0;        // zero before rank's atomicMax
    int g = gtid >> 3;                       // box id
    int j = threadIdx.x & 7;                 // sub-lane 0..7
    if (g >= BATCH * NBOX) return;

    const float* l = logits + (long)g * NCLS;
    float M = -3.0e38f;
    float bl = -3.0e38f; int bc = 0;
    for (int c = j; c < NCLS; c += 8) {
        float v = l[c];
        M = fmaxf(M, v);
        if (c >= 1 && v > bl) { bl = v; bc = c; }
    }
    #pragma unroll
    for (int off = 1; off < 8; off <<= 1)
        M = fmaxf(M, __shfl_xor(M, off));
    float S = 0.f;
    for (int c = j; c < NCLS; c += 8) S += expf(l[c] - M);
    #pragma unroll
    for (int off = 1; off < 8; off <<= 1) S += __shfl_xor(S, off);
    #pragma unroll
    for (int off = 1; off < 8; off <<= 1) {
        float ov = __shfl_xor(bl, off);
        int   oi = __shfl_xor(bc, off);
        if (ov > bl || (ov == bl && oi < bc)) { bl = ov; bc = oi; }
    }
    if (j == 0) {
        float score = expf(bl - M) / S;
        const float* p = proposals + (long)g * 5;
        float y1 = p[0], x1 = p[1], y2 = p[2], x2 = p[3];
        float h = y2 - y1, w = x2 - x1;
        float cy = (y2 + y1) * 0.5f, cx = (x2 + x1) * 0.5f;
        const float* dd = deltas + ((long)g * NCLS + bc) * 4;
        float d0 = dd[0] * 0.1f, d1 = dd[1] * 0.1f;
        float d2 = dd[2] * 0.2f, d3 = dd[3] * 0.2f;
        cy = cy + d0 * h;
        cx = cx + d1 * w;
        h = h * expf(d2);
        w = w * expf(d3);
        boxes_out[g] = make_float4(cy - h * 0.5f, cx - w * 0.5f,
                                   cy + h * 0.5f, cx + w * 0.5f);
        scores_out[g] = score;
    }
}

// ---- rank: stable descending sort via direct rank, 512 thr (2 waves/SIMD) ----
__global__ __launch_bounds__(512) void rank_kernel(
        const float* __restrict__ scores,
        const float4* __restrict__ boxes,
        unsigned long long* __restrict__ skey,
        float4* __restrict__ sbox,
        int* __restrict__ Larr) {
    int bid = blockIdx.x;
    int b = bid & 7, rb = bid >> 3;      // batch = bid%8 -> XCD locality
    int t = threadIdx.x;

    __shared__ unsigned long long s_key[NPAD + 16];
    __shared__ int s_part[64][8];

    for (int c = t; c < NPAD; c += 512) {
        unsigned int bits = 0u;
        if (c < NBOX) bits = __float_as_uint(scores[b * NBOX + c]);
        s_key[c + (c >> 7)] =
            ((unsigned long long)bits << 32) |
            (unsigned long long)(0xFFFFFFFFu - (unsigned)c);
    }
    __syncthreads();

    int own = rb * 64 + (t >> 3);
    int seg = t & 7;
    unsigned long long mykey = s_key[own + (own >> 7)];
    int cnt = 0;
    int cbase = seg * 256;
    #pragma unroll 4
    for (int jj = 0; jj < 256; ++jj) {
        int c = cbase + jj;
        cnt += (s_key[c + (c >> 7)] > mykey) ? 1 : 0;
    }
    s_part[t >> 3][seg] = cnt;
    __syncthreads();

    if (t < 64) {
        int own2 = rb * 64 + t;
        unsigned long long key = s_key[own2 + (own2 >> 7)];
        int rank = s_part[t][0] + s_part[t][1] + s_part[t][2] + s_part[t][3]
                 + s_part[t][4] + s_part[t][5] + s_part[t][6] + s_part[t][7];
        skey[b * NPAD + rank] = key;
        unsigned int orig = 0xFFFFFFFFu - (unsigned int)key;
        float4 bx = make_float4(0.f, 0.f, 0.f, 0.f);
        if (orig < NBOX) bx = boxes[b * NBOX + orig];
        sbox[b * NPAD + rank] = bx;
        float sc = __uint_as_float((unsigned int)(key >> 32));
        if (sc > SCORE_T) atomicMax(&Larr[b], rank + 1);
    }
}

// ---- mask: upper-triangle x alive-prefix compute, full-row stores, 512 thr ----
__global__ __launch_bounds__(512) void mask_kernel(
        const float4* __restrict__ sbox,
        const int* __restrict__ Larr,
        unsigned int* __restrict__ mask) {
    int bid = blockIdx.x;
    int b = bid & 7, rb = bid >> 3;      // batch = bid%8 -> same XCD as walk block b
    int L = Larr[b];
    if (rb * 64 >= L) return;            // uniform: no row of this block is ever read
    int t = threadIdx.x;

    __shared__ float4 s_bx[NPAD + 16];

    for (int c = t; c < NPAD; c += 512)
        s_bx[c + (c >> 7)] = sbox[b * NPAD + c];
    __syncthreads();

    int r   = rb * 64 + (t & 63);        // lanes of a wave = 64 consecutive rows
    int seg = t >> 6;                    // word segment 0..7 (8 words each)
    float4 rbx = s_bx[r + (r >> 7)];
    float rar = (rbx.z - rbx.x) * (rbx.w - rbx.y);
    unsigned int* outp = mask + (((size_t)(b * NPAD + r)) << 6);

    for (int w = 0; w < 8; ++w) {
        int wi = (seg << 3) + w;
        unsigned int bits = 0u;
        int colbase = wi << 5;
        if (colbase + 31 > r && colbase < L) {
            #pragma unroll 8
            for (int c2 = 0; c2 < 32; ++c2) {
                int col = colbase + c2;
                float4 ob = s_bx[col + (col >> 7)];
                float oa = (ob.z - ob.x) * (ob.w - ob.y);
                float yy1 = fmaxf(rbx.x, ob.x), xx1 = fmaxf(rbx.y, ob.y);
                float yy2 = fminf(rbx.z, ob.z), xx2 = fminf(rbx.w, ob.w);
                float inter = fmaxf(yy2 - yy1, 0.f) * fmaxf(xx2 - xx1, 0.f);
                float iou = inter / (rar + oa - inter + 1e-8f);  // IEEE fdiv: exact vs ref
                bits |= (iou > IOU_T) ? (1u << c2) : 0u;
            }
        }
        outp[wi] = bits;
    }
}

// ---- walk: 64-candidate batches, parallel extraction + ballot-transpose
//      pairwise resolve (r12-proven: loads not shuffles), scalar greedy commit ----
__global__ __launch_bounds__(64) void walk_kernel(
        const int* __restrict__ Larr,
        const unsigned int* __restrict__ mask,
        int* __restrict__ klist,
        int* __restrict__ kcount) {
    int b = blockIdx.x;
    int lane = threadIdx.x;

    __shared__ int s_cand[WDEPTH];
    __shared__ unsigned int s_clrw[64];
    __shared__ int s_kl[MAX_OUT];

    int L = Larr[b];
    int nset = L - (lane << 5);
    nset = nset < 0 ? 0 : (nset > 32 ? 32 : nset);
    unsigned int alive = (nset >= 32) ? 0xFFFFFFFFu
                        : ((nset <= 0) ? 0u : ((1u << nset) - 1u));

    const unsigned int* M = mask + ((size_t)b * NPAD) * MASK_WORDS;
    int kept = 0;

    while (kept < MAX_OUT) {
        unsigned long long ne = __ballot(alive != 0u);
        if (!ne) break;

        // ---- parallel extraction of first up-to-64 alive (ascending rank) ----
        int mypc = __builtin_popcount(alive);
        int incl = mypc;
        #pragma unroll
        for (int off = 1; off < 64; off <<= 1) {
            int n = __shfl_up(incl, off);
            if (lane >= off) incl += n;
        }
        int excl = incl - mypc;
        int total = __builtin_amdgcn_readlane(incl, 63);
        int ncand = total < WDEPTH ? total : WDEPTH;

        {   // each lane peels its own word into s_cand (parallel across lanes)
            unsigned int aw = alive;
            int pos = excl;
            while (aw && pos < WDEPTH) {
                int bit = (int)__builtin_ctz(aw);
                aw &= aw - 1u;
                s_cand[pos] = (lane << 5) + bit;
                pos++;
            }
        }
        __syncthreads();

        int candv = s_cand[lane < ncand ? lane : 0];

        // broadcast candidate ids to scalars (independent readlanes, pipelined)
        int cdsc[WDEPTH];
        #pragma unroll
        for (int d = 0; d < WDEPTH; ++d)
            cdsc[d] = __builtin_amdgcn_readlane(candv, d);

        // rowA[d]: word `lane` of row cand_d  (for alive update)
        unsigned int rowA[WDEPTH];
        #pragma unroll
        for (int d = 0; d < WDEPTH; ++d)
            rowA[d] = M[((size_t)cdsc[d] << 6) + lane];

        // colw[e]: the word of row cand_e containing MY candidate's bit
        unsigned int colw[WDEPTH];
        int myw = candv >> 5;
        #pragma unroll
        for (int e = 0; e < WDEPTH; ++e)
            colw[e] = M[((size_t)cdsc[e] << 6) + myw];

        // suppression column for my candidate: bit e = cand_e suppresses me
        int sh = candv & 31;
        unsigned int colv_lo = 0u, colv_hi = 0u;
        #pragma unroll
        for (int e = 0; e < 32; ++e)
            colv_lo |= ((colw[e] >> sh) & 1u) << e;
        #pragma unroll
        for (int e = 32; e < WDEPTH; ++e)
            colv_hi |= ((colw[e] >> sh) & 1u) << (e - 32);

        // transpose columns -> scalar row masks sub[e] (bit d = e suppresses d)
        unsigned long long sub[WDEPTH];
        #pragma unroll
        for (int e = 0; e < 32; ++e)
            sub[e] = __ballot(((colv_lo >> e) & 1u) != 0u);
        #pragma unroll
        for (int e = 32; e < WDEPTH; ++e)
            sub[e] = __ballot(((colv_hi >> (e - 32)) & 1u) != 0u);

        // ---- scalar greedy resolve over the batch (exact order + MAX_OUT) ----
        unsigned long long live =
            (ncand >= 64) ? ~0ull : ((1ull << ncand) - 1ull);
        unsigned long long committed = 0ull;
        int kept_base = kept;
        #pragma unroll
        for (int e = 0; e < WDEPTH; ++e) {
            if (kept < MAX_OUT && ((live >> e) & 1ull)) {
                committed |= 1ull << e;
                kept++;
                live &= ~sub[e];
            }
        }

        // alive update: committed rows clear their suppressees (incl. all
        // killed batch candidates); branchless scalar-masked OR
        unsigned int acc = 0u;
        #pragma unroll
        for (int d = 0; d < WDEPTH; ++d) {
            unsigned int m = 0u - (unsigned int)((committed >> d) & 1ull);
            acc |= rowA[d] & m;
        }
        alive &= ~acc;

        // clear committed candidates' own bits (self-bit in mask unreliable)
        s_clrw[lane] = 0u;
        __syncthreads();
        if (lane < ncand && ((committed >> lane) & 1ull))
            atomicOr(&s_clrw[candv >> 5], 1u << (candv & 31));
        __syncthreads();
        alive &= ~s_clrw[lane];

        // record kept ids in order (parallel: rank = popcount of earlier commits)
        if (lane < ncand && ((committed >> lane) & 1ull)) {
            int pos = kept_base +
                (int)__builtin_popcountll(committed & ((1ull << lane) - 1ull));
            s_kl[pos] = candv;
        }
        __syncthreads();
    }

    if (lane == 0) kcount[b] = kept;
    __syncthreads();
    for (int k = lane; k < kept; k += 64)
        klist[b * MAX_OUT + k] = s_kl[k];
}

// ---------------- outputs: parallel gather + zero-fill ----------------
__global__ void out_kernel(const unsigned long long* __restrict__ skey,
                           const float4* __restrict__ sbox,
                           const int* __restrict__ klist,
                           const int* __restrict__ kcount,
                           const float* __restrict__ logits,
                           float* __restrict__ out) {
    int idx = blockIdx.x * blockDim.x + threadIdx.x;
    const int NB = BATCH * MAX_OUT * 5;        // 12000
    const int NS = BATCH * MAX_OUT * 2;        // 4800
    const int NL = BATCH * MAX_OUT * NCLS;     // 194400
    if (idx >= NB + NS + NL) return;

    if (idx < NB) {
        int b = idx / (MAX_OUT * 5);
        int rem = idx - b * (MAX_OUT * 5);
        int k = rem / 5, c = rem - 5 * k;
        float v = 0.f;
        if (k < kcount[b]) {
            if (c == 4) v = 1.f;
            else {
                float4 bx = sbox[b * NPAD + klist[b * MAX_OUT + k]];
                v = (c == 0) ? bx.x : (c == 1) ? bx.y : (c == 2) ? bx.z : bx.w;
            }
        }
        out[idx] = v;
    } else if (idx < NB + NS) {
        int j = idx - NB;
        int b = j / (MAX_OUT * 2);
        int rem = j - b * (MAX_OUT * 2);
        int k = rem >> 1, c = rem & 1;
        float v = 0.f;
        if (k < kcount[b]) {
            if (c) v = 1.f;
            else {
                unsigned long long key = skey[b * NPAD + klist[b * MAX_OUT + k]];
                v = __uint_as_float((unsigned int)(key >> 32));
            }
        }
        out[idx] = v;
    } else {
        int j = idx - NB - NS;
        int b = j / (MAX_OUT * NCLS);
        int rem = j - b * (MAX_OUT * NCLS);
        int k = rem / NCLS, c = rem - NCLS * k;
        float v = 0.f;
        if (k < kcount[b]) {
            unsigned long long key = skey[b * NPAD + klist[b * MAX_OUT + k]];
            unsigned int orig = 0xFFFFFFFFu - (unsigned int)key;
            v = logits[((long)b * NBOX + orig) * NCLS + c];
        }
        out[idx] = v;
    }
}

extern "C" void kernel_launch(void* const* d_in, const int* in_sizes, int n_in,
                              void* d_out, int out_size, void* d_ws, size_t ws_size,
                              hipStream_t stream) {
    const float* deltas    = (const float*)d_in[0];
    const float* logits    = (const float*)d_in[1];
    const float* proposals = (const float*)d_in[2];
    float* out = (float*)d_out;

    char* ws = (char*)d_ws;
    float4* ws_boxes  = (float4*)(ws + WS_BOXES);
    float*  ws_scores = (float*)(ws + WS_SCORES);
    unsigned long long* ws_skey = (unsigned long long*)(ws + WS_SKEY);
    float4* ws_sbox   = (float4*)(ws + WS_SBOX);
    int*    ws_Larr   = (int*)(ws + WS_LARR);
    int*    ws_klist  = (int*)(ws + WS_KLIST);
    int*    ws_kcount = (int*)(ws + WS_KCOUNT);
    unsigned int* ws_mask = (unsigned int*)(ws + WS_MASK);

    prep_kernel<<<(BATCH * NBOX * 8 + 255) / 256, 256, 0, stream>>>(
        deltas, logits, proposals, ws_boxes, ws_scores, ws_Larr);
    rank_kernel<<<BATCH * (NPAD / 64), 512, 0, stream>>>(
        ws_scores, ws_boxes, ws_skey, ws_sbox, ws_Larr);
    mask_kernel<<<BATCH * (NPAD / 64), 512, 0, stream>>>(
        ws_sbox, ws_Larr, ws_mask);
    walk_kernel<<<BATCH, 64, 0, stream>>>(
        ws_Larr, ws_mask, ws_klist, ws_kcount);
    int total_out = BATCH * MAX_OUT * (5 + 2 + NCLS);
    out_kernel<<<(total_out + 255) / 256, 256, 0, stream>>>(
        ws_skey, ws_sbox, ws_klist, ws_kcount, logits, out);
}